// Round 1
// baseline (134.505 us; speedup 1.0000x reference)
//
#include <hip/hip_runtime.h>

#define N_IMG 8
#define K_INS 16
#define CCH   64
#define EPSV  1e-5f

// workspace layout (bytes):
//   [0, 65536)          float2 stats[N][K][C]   (sum, sumsq)  -- fully written each call
//   [65536, 66048)      int    cnt[N][K]        -- zeroed via hipMemsetAsync each call
//   [66048, 131584)     float2 scsh[N][K][C]    (scale, shift) -- fully written each call
#define STATS_OFF 0
#define CNT_OFF   65536
#define SCSH_OFF  66048

__global__ __launch_bounds__(256) void count_kernel(const int* __restrict__ ids,
                                                    int* __restrict__ cnt, int HW) {
    // grid: (tilesPerImg=32, N). tile = HW/32 ids; each of 4 waves takes a quarter.
    const int n = blockIdx.y;
    const int tileSize = HW / 32;
    const int quarter = tileSize / 4;
    const int lane = threadIdx.x & 63;
    const int wave = threadIdx.x >> 6;
    const int wbase = blockIdx.x * tileSize + wave * quarter;
    const int* p = ids + (size_t)n * HW;

    int myc[K_INS];
#pragma unroll
    for (int k = 0; k < K_INS; ++k) myc[k] = 0;

    for (int i = wbase + lane; i < wbase + quarter; i += 64) {
        int id = p[i];
#pragma unroll
        for (int k = 0; k < K_INS; ++k) {
            unsigned long long m = __ballot(id == k);
            if (lane == 0) myc[k] += __popcll(m);
        }
    }
    if (lane == 0) {
#pragma unroll
        for (int k = 0; k < K_INS; ++k) atomicAdd(&cnt[n * K_INS + k], myc[k]);
    }
}

__device__ __forceinline__ void accum(float2 (*A)[256], int t, float v, int id) {
    if (id >= 0) {
        float2 s = A[id][t];
        s.x += v;
        s.y += v * v;
        A[id][t] = s;
    }
}

__global__ __launch_bounds__(256) void stats_kernel(const float* __restrict__ x,
                                                    const int* __restrict__ ids,
                                                    float2* __restrict__ stats, int HW) {
    // grid: (C, N). Block owns one (n,c): accumulates sum/sumsq for all K instances.
    const int c = blockIdx.x;
    const int n = blockIdx.y;
    const int t = threadIdx.x;

    // per-thread-private LDS accumulators; two copies (A/B) = two independent
    // LDS RMW chains per thread for latency overlap. 64 KB total -> 2 blocks/CU.
    __shared__ float2 accA[K_INS][256];
    __shared__ float2 accB[K_INS][256];
#pragma unroll
    for (int k = 0; k < K_INS; ++k) {
        accA[k][t] = make_float2(0.f, 0.f);
        accB[k][t] = make_float2(0.f, 0.f);
    }
    __syncthreads();

    const float* xp = x + ((size_t)n * CCH + c) * HW;
    const int* ip = ids + (size_t)n * HW;
    const int half = HW / 2;

    const float4* xa4 = (const float4*)(xp);
    const float4* xb4 = (const float4*)(xp + half);
    const int4* ia4 = (const int4*)(ip);
    const int4* ib4 = (const int4*)(ip + half);

    const int iters = half / (256 * 4);
    for (int j = 0; j < iters; ++j) {
        int idx = j * 256 + t;
        float4 xa = xa4[idx];
        int4 ia = ia4[idx];
        float4 xb = xb4[idx];
        int4 ib = ib4[idx];
        accum(accA, t, xa.x, ia.x);
        accum(accB, t, xb.x, ib.x);
        accum(accA, t, xa.y, ia.y);
        accum(accB, t, xb.y, ib.y);
        accum(accA, t, xa.z, ia.z);
        accum(accB, t, xb.z, ib.z);
        accum(accA, t, xa.w, ia.w);
        accum(accB, t, xb.w, ib.w);
    }
    __syncthreads();

    // reduce: wave w handles k in [w*4, w*4+4)
    const int wave = t >> 6, lane = t & 63;
#pragma unroll
    for (int kk = 0; kk < 4; ++kk) {
        int k = wave * 4 + kk;
        float2 s = accA[k][lane];
#pragma unroll
        for (int q = 1; q < 4; ++q) {
            float2 a = accA[k][lane + 64 * q];
            s.x += a.x;
            s.y += a.y;
        }
#pragma unroll
        for (int q = 0; q < 4; ++q) {
            float2 b = accB[k][lane + 64 * q];
            s.x += b.x;
            s.y += b.y;
        }
#pragma unroll
        for (int off = 32; off > 0; off >>= 1) {
            s.x += __shfl_down(s.x, off);
            s.y += __shfl_down(s.y, off);
        }
        if (lane == 0) stats[((size_t)n * K_INS + k) * CCH + c] = s;
    }
}

__global__ __launch_bounds__(256) void finalize_kernel(const float2* __restrict__ stats,
                                                       const int* __restrict__ cnt,
                                                       const float* __restrict__ gamma,
                                                       const float* __restrict__ beta,
                                                       float2* __restrict__ scsh) {
    int i = blockIdx.x * 256 + threadIdx.x;  // over N*K*C = 8192
    if (i >= N_IMG * K_INS * CCH) return;
    int c = i % CCH;
    int nk = i / CCH;
    float2 s = stats[i];
    float denom = fmaxf((float)cnt[nk], 1.0f);
    float mean = s.x / denom;
    float var = s.y / denom - mean * mean;
    float r = rsqrtf(var + EPSV);
    float sc = r * gamma[c];
    float sh = beta[c] - mean * sc;
    scsh[i] = make_float2(sc, sh);
}

__global__ __launch_bounds__(256) void norm_kernel(const float* __restrict__ x,
                                                   const int* __restrict__ ids,
                                                   const float2* __restrict__ scsh,
                                                   float* __restrict__ out, int HW) {
    // grid: (C, N)
    const int c = blockIdx.x;
    const int n = blockIdx.y;
    const int t = threadIdx.x;

    __shared__ float2 ls[K_INS];
    if (t < K_INS) ls[t] = scsh[((size_t)n * K_INS + t) * CCH + c];
    __syncthreads();

    const float4* xp = (const float4*)(x + ((size_t)n * CCH + c) * HW);
    const int4* ip = (const int4*)(ids + (size_t)n * HW);
    float4* op = (float4*)(out + ((size_t)n * CCH + c) * HW);

    const int iters = HW / (256 * 4);
    for (int j = 0; j < iters; ++j) {
        int idx = j * 256 + t;
        float4 xv = xp[idx];
        int4 id = ip[idx];
        float4 o;
        {
            float2 ss = ls[max(id.x, 0)];
            o.x = (id.x >= 0) ? fmaf(xv.x, ss.x, ss.y) : xv.x;
        }
        {
            float2 ss = ls[max(id.y, 0)];
            o.y = (id.y >= 0) ? fmaf(xv.y, ss.x, ss.y) : xv.y;
        }
        {
            float2 ss = ls[max(id.z, 0)];
            o.z = (id.z >= 0) ? fmaf(xv.z, ss.x, ss.y) : xv.z;
        }
        {
            float2 ss = ls[max(id.w, 0)];
            o.w = (id.w >= 0) ? fmaf(xv.w, ss.x, ss.y) : xv.w;
        }
        op[idx] = o;
    }
}

extern "C" void kernel_launch(void* const* d_in, const int* in_sizes, int n_in,
                              void* d_out, int out_size, void* d_ws, size_t ws_size,
                              hipStream_t stream) {
    const float* x = (const float*)d_in[0];
    const int* ids = (const int*)d_in[1];
    const float* gamma = (const float*)d_in[2];
    const float* beta = (const float*)d_in[3];
    float* out = (float*)d_out;

    const int HW = in_sizes[1] / N_IMG;  // 65536

    float2* stats = (float2*)((char*)d_ws + STATS_OFF);
    int* cnt = (int*)((char*)d_ws + CNT_OFF);
    float2* scsh = (float2*)((char*)d_ws + SCSH_OFF);

    // counts are accumulated with atomics -> must be zeroed every call
    hipMemsetAsync((char*)d_ws + CNT_OFF, 0, N_IMG * K_INS * sizeof(int), stream);

    count_kernel<<<dim3(32, N_IMG), 256, 0, stream>>>(ids, cnt, HW);
    stats_kernel<<<dim3(CCH, N_IMG), 256, 0, stream>>>(x, ids, stats, HW);
    finalize_kernel<<<dim3((N_IMG * K_INS * CCH + 255) / 256), 256, 0, stream>>>(
        stats, cnt, gamma, beta, scsh);
    norm_kernel<<<dim3(CCH, N_IMG), 256, 0, stream>>>(x, ids, scsh, out, HW);
}